// Round 7
// baseline (116.902 us; speedup 1.0000x reference)
//
#include <hip/hip_runtime.h>
#include <hip/hip_bf16.h>

// ---------------------------------------------------------------------------
// B=2, L=64, H=W=64. SINGLE dispatch:
//   each of 512 co-resident blocks repacks 1/512 of the weights into ws
//   (bf16 MFMA A-fragment layouts), device-scope arrive counter (base =
//   harness 0xAA poison), stages its x-tile during the wait, acquire-spins,
//   then: conv1 (flat-N MFMA) -> r1(LDS) -> conv2 (MFMA) -> h(LDS) ->
//   qkv via MFMA -> fused l2norm -> softmax (exp2) -> out-proj via MFMA ->
//   +bias+residual -> global store. h never touches HBM.
// ---------------------------------------------------------------------------

#define IMG 262144

using frag_ab = __attribute__((ext_vector_type(8))) short;  // 8 bf16
using frag_cd = __attribute__((ext_vector_type(4))) float;  // 4 fp32
typedef unsigned u32x4 __attribute__((ext_vector_type(4)));
typedef float    f32x2 __attribute__((ext_vector_type(2)));
typedef float    f32x4 __attribute__((ext_vector_type(4)));

static __device__ inline unsigned short f2bf(float f) {
    unsigned u = __float_as_uint(f);
    return (unsigned short)((u + 0x7FFFu + ((u >> 16) & 1u)) >> 16);
}
static __device__ inline unsigned packbf(float a, float b) {
    return (unsigned)f2bf(a) | ((unsigned)f2bf(b) << 16);
}

#if __has_builtin(__builtin_amdgcn_exp2f)
#define EXP2F(x) __builtin_amdgcn_exp2f(x)
#else
#define EXP2F(x) __expf(0.6931471805599453f * (x))
#endif

// ---------------- fully fused single kernel --------------------------------
// Grid 512 = 2 b x 64 y x 4 xstrips(16); 2 blocks/CU -> all co-resident.
// 4 waves; wave w owns channel slice [16w,16w+16) in all matmul phases.
__global__ __launch_bounds__(256, 2) void mega_k(
    const float* __restrict__ x,
    const float* __restrict__ w1, const float* __restrict__ b1,
    const float* __restrict__ w2, const float* __restrict__ b2,
    const float* __restrict__ wq, const float* __restrict__ wk,
    const float* __restrict__ wv, const float* __restrict__ wo,
    const float* __restrict__ bo,
    unsigned short* wt1, unsigned short* wt2, unsigned short* wa,
    unsigned* cnt, float* __restrict__ out)
{
    __shared__ __align__(16) unsigned short xt[5 * 20 * 72];  // 14400 B
    __shared__ __align__(16) unsigned short r1[54 * 72];      //  7776 B
    __shared__ __align__(16) float          t_lds[16 * 68];   //  4352 B
    __shared__ __align__(16) unsigned       tp[16 * 36];      //  2304 B
    __shared__ __align__(16) f32x2          kv[16 * 66];      //  8448 B (raw k,v)
    __shared__ __align__(16) unsigned       o_l32[16 * 36];   //  2304 B
    __shared__ __align__(16) f32x2          nrm[4 * 17];      //   544 B

    const int tid  = threadIdx.x;
    const int b    = blockIdx.x >> 8;
    const int y    = (blockIdx.x >> 2) & 63;
    const int x0   = (blockIdx.x & 3) * 16;
    const int wv_  = tid >> 6;
    const int lane = tid & 63;
    const int m    = lane & 15;
    const int qd   = lane >> 4;
    const int oc0  = wv_ * 16;

    // ---- phase 0: this block's 1/512 slice of weight repacking ----
    // Conv: wt[((t*4+g)*2+s)*64+lane]*8 holds w[oc=16g+mm][ic=32s+8qq+e].
    // Attn: wa[mat*4096 + j], same A-frag layout. Writes are block-aligned
    // 64B lines (no cross-block line sharing).
    {
        int gid = blockIdx.x * 256 + tid;
        if (gid < 73728) {
            int mat = gid >= 36864;
            int j = gid - mat * 36864;
            int tap = j >> 12;
            int oc  = (j >> 6) & 63;
            int ic  = j & 63;
            const float* w = mat ? w2 : w1;
            int g = oc >> 4, mm = oc & 15;
            int s = ic >> 5, qq = (ic >> 3) & 3, e = ic & 7;
            int dst = ((((tap * 4 + g) * 2 + s) * 4 + qq) * 16 + mm) * 8 + e;
            (mat ? wt2 : wt1)[dst] = f2bf(w[(oc * 64 + ic) * 9 + tap]);
        } else if (gid < 90112) {
            int a = gid - 73728;
            int mat = a >> 12;
            int j = a & 4095;
            int e     = j & 7;
            int lane2 = (j >> 3) & 63;
            int gs    = j >> 9;
            int g = gs >> 1, s = gs & 1;
            int qq = lane2 >> 4, mm = lane2 & 15;
            int oc = 16 * g + mm;
            int ic = 32 * s + 8 * qq + e;
            const float* w = (mat == 0) ? wq : (mat == 1) ? wk
                           : (mat == 2) ? wv : wo;
            wa[mat * 4096 + j] = f2bf(w[oc * 64 + ic]);
        }
    }
    __syncthreads();                       // order block's prep stores
    if (tid == 0) {
        __threadfence();                   // device-scope release of stores
        __hip_atomic_fetch_add(cnt, 1u, __ATOMIC_RELEASE,
                               __HIP_MEMORY_SCOPE_AGENT);
    }

    // ---- stage x tile rows y-2..y+2 (overlaps other blocks' prep) ----
    #pragma unroll
    for (int it = 0; it < 10; ++it) {
        int e    = it * 256 + tid;        // 0..2559
        int grp  = e & 7;
        int pair = e >> 3;                // 0..319
        int row = pair >> 6, ic = pair & 63;
        int yy = y - 2 + row;
        int yc = min(max(yy, 0), 63);
        int gx0 = x0 - 8 + grp * 4;
        int gxl = min(max(gx0, 0), 60);
        f32x4 v = *(const f32x4*)&x[((b * 64 + ic) * 64 + yc) * 64 + gxl];
        #pragma unroll
        for (int j = 0; j < 4; ++j) {
            int gx  = gx0 + j;
            int xsl = gx - x0 + 2;
            if (xsl < 0 || xsl >= 20) continue;
            unsigned short val =
                (yy == yc && gx >= 0 && gx <= 63) ? f2bf(v[j]) : (unsigned short)0;
            xt[(row * 20 + xsl) * 72 + ic] = val;
        }
    }

    // ---- wait: all 512 blocks' prep visible (counter base = 0xAA poison) ----
    if (tid == 0) {
        const unsigned base = 0xAAAAAAAAu;
        for (int it = 0; it < 200000; ++it) {
            unsigned v = __hip_atomic_load(cnt, __ATOMIC_ACQUIRE,
                                           __HIP_MEMORY_SCOPE_AGENT);
            if ((unsigned)(v - base) >= 512u) break;
            __builtin_amdgcn_s_sleep(2);
        }
    }
    __syncthreads();   // staging done + weights ready (post-acquire)

    // ---- A1 fragments: lane-coalesced 1KB loads ----
    frag_ab A1[9][2];
    #pragma unroll
    for (int t = 0; t < 9; ++t)
        #pragma unroll
        for (int s = 0; s < 2; ++s)
            A1[t][s] = *(const frag_ab*)&wt1[(((t * 4 + wv_) * 2 + s) * 64 + lane) * 8];

    // ---- conv1: flat N = (row 0..2) x (xs 0..17) = 54, 4 tiles of 16 ----
    int pb[4], rn_[4], xs_[4];
    bool nv[4];
    #pragma unroll
    for (int nt = 0; nt < 4; ++nt) {
        int n  = nt * 16 + m;
        int nc = min(n, 53);
        int rr = nc / 18, xx = nc - rr * 18;
        rn_[nt] = rr; xs_[nt] = xx; nv[nt] = (n < 54);
        pb[nt] = (rr * 20 + xx) * 72 + qd * 8;
    }
    frag_cd acc1[4];
    #pragma unroll
    for (int i = 0; i < 4; ++i) acc1[i] = (frag_cd){0.f, 0.f, 0.f, 0.f};

    #pragma unroll
    for (int ky = 0; ky < 3; ++ky)
        #pragma unroll
        for (int kx = 0; kx < 3; ++kx)
            #pragma unroll
            for (int s = 0; s < 2; ++s) {
                frag_ab a = A1[ky * 3 + kx][s];
                int off = (ky * 20 + kx) * 72 + s * 32;
                #pragma unroll
                for (int nt = 0; nt < 4; ++nt)
                    acc1[nt] = __builtin_amdgcn_mfma_f32_16x16x32_bf16(
                        a, *(const frag_ab*)&xt[pb[nt] + off], acc1[nt], 0, 0, 0);
            }

    // ---- A2 + attn A-fragments (latency overlaps epilogue + barrier) ----
    frag_ab A2[9][2];
    #pragma unroll
    for (int t = 0; t < 9; ++t)
        #pragma unroll
        for (int s = 0; s < 2; ++s)
            A2[t][s] = *(const frag_ab*)&wt2[(((t * 4 + wv_) * 2 + s) * 64 + lane) * 8];
    frag_ab Aq[2], Ak[2], Av[2], Ao[2];
    #pragma unroll
    for (int s = 0; s < 2; ++s) {
        int off = ((wv_ * 2 + s) * 64 + lane) * 8;
        Aq[s] = *(const frag_ab*)&wa[off];
        Ak[s] = *(const frag_ab*)&wa[4096 + off];
        Av[s] = *(const frag_ab*)&wa[8192 + off];
        Ao[s] = *(const frag_ab*)&wa[12288 + off];
    }

    // ---- r1 = bf16(relu(conv1+b1)), zero at image edges ----
    {
        frag_cd b1f = *(const frag_cd*)&b1[oc0 + qd * 4];
        #pragma unroll
        for (int nt = 0; nt < 4; ++nt) {
            if (!nv[nt]) continue;
            int n = nt * 16 + m;
            int gy = y - 1 + rn_[nt];
            int gx = x0 - 1 + xs_[nt];
            bool oob = (gy < 0) | (gy > 63) | (gx < 0) | (gx > 63);
            #pragma unroll
            for (int r = 0; r < 4; ++r) {
                float v = fmaxf(acc1[nt][r] + b1f[r], 0.f);
                r1[n * 72 + oc0 + qd * 4 + r] = oob ? (unsigned short)0 : f2bf(v);
            }
        }
    }
    __syncthreads();

    // ---- conv2: 1 N-tile (16 tokens), 18 MFMA/wave ----
    frag_cd acc2 = (frag_cd){0.f, 0.f, 0.f, 0.f};
    #pragma unroll
    for (int ky = 0; ky < 3; ++ky)
        #pragma unroll
        for (int kx = 0; kx < 3; ++kx)
            #pragma unroll
            for (int s = 0; s < 2; ++s)
                acc2 = __builtin_amdgcn_mfma_f32_16x16x32_bf16(
                    A2[ky * 3 + kx][s],
                    *(const frag_ab*)&r1[(ky * 18 + m + kx) * 72 + s * 32 + qd * 8],
                    acc2, 0, 0, 0);

    // ---- h -> t_lds (fp32 residual) + tp (bf16 pairs, stride 36) ----
    {
        frag_cd b2f = *(const frag_cd*)&b2[oc0 + qd * 4];
        f32x4 hv;
        #pragma unroll
        for (int r = 0; r < 4; ++r) hv[r] = acc2[r] + b2f[r];
        *(f32x4*)&t_lds[m * 68 + oc0 + qd * 4] = hv;
        int dpb = m * 36 + (oc0 >> 1) + qd * 2;
        tp[dpb + 0] = packbf(hv[0], hv[1]);
        tp[dpb + 1] = packbf(hv[2], hv[3]);
    }
    __syncthreads();

    // ---- qkv via MFMA: wave w -> channels [16w,16w+16) x 16 tokens ----
    frag_cd qA = (frag_cd){0,0,0,0}, kA = (frag_cd){0,0,0,0}, vA = (frag_cd){0,0,0,0};
    #pragma unroll
    for (int s = 0; s < 2; ++s) {
        frag_ab hfrag = *(const frag_ab*)&tp[m * 36 + s * 16 + qd * 4];
        qA = __builtin_amdgcn_mfma_f32_16x16x32_bf16(Aq[s], hfrag, qA, 0, 0, 0);
        kA = __builtin_amdgcn_mfma_f32_16x16x32_bf16(Ak[s], hfrag, kA, 0, 0, 0);
        vA = __builtin_amdgcn_mfma_f32_16x16x32_bf16(Av[s], hfrag, vA, 0, 0, 0);
    }
    // D layout: lane(qd,m) reg r = {q,k,v}[ch=16w+4qd+r][tok=m]

    // ---- raw k,v to LDS + norm partials; ONE barrier; fold rq*rk into q ----
    float nq = qA[0]*qA[0] + qA[1]*qA[1] + qA[2]*qA[2] + qA[3]*qA[3];
    float nk = kA[0]*kA[0] + kA[1]*kA[1] + kA[2]*kA[2] + kA[3]*kA[3];
    nq += __shfl_xor(nq, 16); nq += __shfl_xor(nq, 32);
    nk += __shfl_xor(nk, 16); nk += __shfl_xor(nk, 32);
    if (qd == 0) nrm[wv_ * 17 + m] = (f32x2){nq, nk};
    #pragma unroll
    for (int r = 0; r < 4; ++r)
        kv[m * 66 + oc0 + qd * 4 + r] = (f32x2){kA[r], vA[r]};   // raw
    __syncthreads();

    f32x2 p0 = nrm[m],      p1 = nrm[17 + m];
    f32x2 p2 = nrm[34 + m], p3 = nrm[51 + m];
    float snq = p0.x + p1.x + p2.x + p3.x;
    float snk = p0.y + p1.y + p2.y + p3.y;
    float qs = 1.4426950408889634f /
               fmaxf(fmaxf(sqrtf(snq), 1e-12f) * fmaxf(sqrtf(snk), 1e-12f) /
                     fmaxf(sqrtf(snk), 1e-12f) * fmaxf(sqrtf(snk), 1e-12f), 1e-24f);
    // (simplified below — compute directly)
    qs = 1.4426950408889634f /
         (fmaxf(sqrtf(snq), 1e-12f) * fmaxf(sqrtf(snk), 1e-12f));
    float qn[4];
    #pragma unroll
    for (int r = 0; r < 4; ++r) qn[r] = qA[r] * qs;

    // ---- softmax over raw k (scale folded into qn): scores bounded ----
    float den[4] = {0, 0, 0, 0}, num[4] = {0, 0, 0, 0};
    #pragma unroll 8
    for (int d2 = 0; d2 < 32; ++d2) {
        f32x4 K = *(const f32x4*)&kv[m * 66 + d2 * 2];   // k0,v0,k1,v1
        #pragma unroll
        for (int r = 0; r < 4; ++r) {
            float e0 = EXP2F(qn[r] * K[0]); den[r] += e0; num[r] = fmaf(e0, K[1], num[r]);
            float e1 = EXP2F(qn[r] * K[2]); den[r] += e1; num[r] = fmaf(e1, K[3], num[r]);
        }
    }
    {
        int ob = m * 36 + wv_ * 8 + qd * 2;
        o_l32[ob + 0] = packbf(num[0] / den[0], num[1] / den[1]);
        o_l32[ob + 1] = packbf(num[2] / den[2], num[3] / den[3]);
    }
    __syncthreads();

    // ---- out-proj via MFMA + bias + residual -> global ----
    frag_cd oA = (frag_cd){0, 0, 0, 0};
    #pragma unroll
    for (int s = 0; s < 2; ++s)
        oA = __builtin_amdgcn_mfma_f32_16x16x32_bf16(
            Ao[s], *(const frag_ab*)&o_l32[m * 36 + s * 16 + qd * 4], oA, 0, 0, 0);

    f32x4 bo4 = *(const f32x4*)&bo[oc0 + qd * 4];
    f32x4 res = *(const f32x4*)&t_lds[m * 68 + oc0 + qd * 4];
    #pragma unroll
    for (int r = 0; r < 4; ++r) {
        float v = oA[r] + bo4[r] + res[r];
        out[((b * 64 + oc0 + qd * 4 + r) * 64 + y) * 64 + x0 + m] = v;
    }
}

extern "C" void kernel_launch(void* const* d_in, const int* in_sizes, int n_in,
                              void* d_out, int out_size, void* d_ws, size_t ws_size,
                              hipStream_t stream) {
    const float* x  = (const float*)d_in[0];
    const float* w1 = (const float*)d_in[1];
    const float* b1 = (const float*)d_in[2];
    const float* w2 = (const float*)d_in[3];
    const float* b2 = (const float*)d_in[4];
    const float* wq = (const float*)d_in[5];
    const float* wk = (const float*)d_in[6];
    const float* wv = (const float*)d_in[7];
    const float* wo = (const float*)d_in[8];
    const float* bo = (const float*)d_in[9];
    float* out = (float*)d_out;

    // ws: wa bf16[16384] (32 KB) | wt1 bf16[36864] | wt2 bf16[36864] |
    //     counter dword at byte 262144 (poisoned 0xAAAAAAAA each launch)
    unsigned short* wa  = (unsigned short*)d_ws;
    unsigned short* wt1 = (unsigned short*)((char*)d_ws + 32768);
    unsigned short* wt2 = wt1 + 36864;
    unsigned*       cnt = (unsigned*)((char*)d_ws + 262144);

    mega_k<<<512, 256, 0, stream>>>(x, w1, b1, w2, b2, wq, wk, wv, wo, bo,
                                    wt1, wt2, wa, cnt, out);
}

// Round 8
// 91.214 us; speedup vs baseline: 1.2816x; 1.2816x over previous
//
#include <hip/hip_runtime.h>
#include <hip/hip_bf16.h>

// ---------------------------------------------------------------------------
// B=2, L=64, H=W=64. Two dispatches (device-barrier single-dispatch REGRESSED
// in R7: cross-XCD acquire/release spin thrashed L2 -> 59us kernel).
//   prep_w: conv weights -> bf16 MFMA A-fragment layout (ws).
//   fused_k: block (b,y,16-strip): conv1 (flat-N MFMA) -> r1(LDS bf16) ->
//            conv2 (MFMA) -> h(LDS) -> qkv via MFMA (attn weights loaded
//            NATIVE fp32, lane-contiguous) -> fused l2norm (single barrier,
//            norms folded into exp2 scale) -> softmax -> out-proj via MFMA ->
//            +bias+residual -> global store from MFMA-D layout.
// ---------------------------------------------------------------------------

#define IMG 262144

using frag_ab = __attribute__((ext_vector_type(8))) short;  // 8 bf16
using frag_cd = __attribute__((ext_vector_type(4))) float;  // 4 fp32
typedef unsigned u32x4 __attribute__((ext_vector_type(4)));
typedef float    f32x2 __attribute__((ext_vector_type(2)));
typedef float    f32x4 __attribute__((ext_vector_type(4)));

static __device__ inline unsigned short f2bf(float f) {
    unsigned u = __float_as_uint(f);
    return (unsigned short)((u + 0x7FFFu + ((u >> 16) & 1u)) >> 16);
}
static __device__ inline unsigned packbf(float a, float b) {
    return (unsigned)f2bf(a) | ((unsigned)f2bf(b) << 16);
}
// 8 fp32 -> one A/B fragment (8 bf16)
static __device__ inline frag_ab pack8(f32x4 a, f32x4 b) {
    union { unsigned u[4]; frag_ab f; } r;
    r.u[0] = packbf(a[0], a[1]);
    r.u[1] = packbf(a[2], a[3]);
    r.u[2] = packbf(b[0], b[1]);
    r.u[3] = packbf(b[2], b[3]);
    return r.f;
}

#if __has_builtin(__builtin_amdgcn_exp2f)
#define EXP2F(x) __builtin_amdgcn_exp2f(x)
#else
#define EXP2F(x) __expf(0.6931471805599453f * (x))
#endif

// ---------------- prep: conv weights -> bf16 A-fragment layout --------------
// wt[((t*4+g)*2+s)*64 + lane]*8 holds w[oc=16g+mm][ic=32s+8qq+e],
// lane = qq*16+mm -> fused A-frag load is one lane-coalesced b128.
__global__ __launch_bounds__(256) void prep_w(
    const float* __restrict__ w1, const float* __restrict__ w2,
    unsigned short* __restrict__ wt1, unsigned short* __restrict__ wt2)
{
    int i = blockIdx.x * 256 + threadIdx.x;      // 0..73727
    int mat = i >= 36864;
    int j = i - mat * 36864;
    int tap = j >> 12;
    int oc  = (j >> 6) & 63;
    int ic  = j & 63;
    const float* w = mat ? w2 : w1;
    int g = oc >> 4, mm = oc & 15;
    int s = ic >> 5, qq = (ic >> 3) & 3, e = ic & 7;
    int dst = ((((tap * 4 + g) * 2 + s) * 4 + qq) * 16 + mm) * 8 + e;
    (mat ? wt2 : wt1)[dst] = f2bf(w[(oc * 64 + ic) * 9 + tap]);
}

// ---------------- fully fused kernel ---------------------------------------
// Grid 512 = 2 b x 64 y x 4 xstrips(16); 2 blocks/CU. 4 waves; wave w owns
// channel slice [16w,16w+16) in all matmul phases.
__global__ __launch_bounds__(256, 2) void fused_k(
    const float* __restrict__ x,
    const unsigned short* __restrict__ wt1, const unsigned short* __restrict__ wt2,
    const float* __restrict__ b1, const float* __restrict__ b2,
    const float* __restrict__ wq, const float* __restrict__ wk,
    const float* __restrict__ wv, const float* __restrict__ wo,
    const float* __restrict__ bo, float* __restrict__ out)
{
    __shared__ __align__(16) unsigned short xt[5 * 20 * 72];  // 14400 B
    __shared__ __align__(16) unsigned short r1[54 * 72];      //  7776 B
    __shared__ __align__(16) float          t_lds[16 * 68];   //  4352 B
    __shared__ __align__(16) unsigned       tp[16 * 36];      //  2304 B
    __shared__ __align__(16) f32x2          kv[16 * 66];      //  8448 B (raw k,v)
    __shared__ __align__(16) unsigned       o_l32[16 * 36];   //  2304 B
    __shared__ __align__(16) f32x2          nrm[4 * 17];      //   544 B

    const int tid  = threadIdx.x;
    const int b    = blockIdx.x >> 8;
    const int y    = (blockIdx.x >> 2) & 63;
    const int x0   = (blockIdx.x & 3) * 16;
    const int wv_  = tid >> 6;
    const int lane = tid & 63;
    const int m    = lane & 15;
    const int qd   = lane >> 4;
    const int oc0  = wv_ * 16;

    // ---- A1 fragments: lane-coalesced 1KB b128 loads from ws ----
    frag_ab A1[9][2];
    #pragma unroll
    for (int t = 0; t < 9; ++t)
        #pragma unroll
        for (int s = 0; s < 2; ++s)
            A1[t][s] = *(const frag_ab*)&wt1[(((t * 4 + wv_) * 2 + s) * 64 + lane) * 8];

    // ---- stage x tile rows y-2..y+2, xslots 0..19 (gx = x0-2+xsl) ----
    #pragma unroll
    for (int it = 0; it < 10; ++it) {
        int e    = it * 256 + tid;        // 0..2559
        int grp  = e & 7;
        int pair = e >> 3;                // 0..319
        int row = pair >> 6, ic = pair & 63;
        int yy = y - 2 + row;
        int yc = min(max(yy, 0), 63);
        int gx0 = x0 - 8 + grp * 4;
        int gxl = min(max(gx0, 0), 60);
        f32x4 v = *(const f32x4*)&x[((b * 64 + ic) * 64 + yc) * 64 + gxl];
        #pragma unroll
        for (int j = 0; j < 4; ++j) {
            int gx  = gx0 + j;
            int xsl = gx - x0 + 2;
            if (xsl < 0 || xsl >= 20) continue;
            unsigned short val =
                (yy == yc && gx >= 0 && gx <= 63) ? f2bf(v[j]) : (unsigned short)0;
            xt[(row * 20 + xsl) * 72 + ic] = val;
        }
    }
    __syncthreads();

    // ---- conv1: flat N = (row 0..2) x (xs 0..17) = 54, 4 tiles of 16 ----
    int pb[4], rn_[4], xs_[4];
    bool nv[4];
    #pragma unroll
    for (int nt = 0; nt < 4; ++nt) {
        int n  = nt * 16 + m;
        int nc = min(n, 53);
        int rr = nc / 18, xx = nc - rr * 18;
        rn_[nt] = rr; xs_[nt] = xx; nv[nt] = (n < 54);
        pb[nt] = (rr * 20 + xx) * 72 + qd * 8;
    }
    frag_cd acc1[4];
    #pragma unroll
    for (int i = 0; i < 4; ++i) acc1[i] = (frag_cd){0.f, 0.f, 0.f, 0.f};

    #pragma unroll
    for (int ky = 0; ky < 3; ++ky)
        #pragma unroll
        for (int kx = 0; kx < 3; ++kx)
            #pragma unroll
            for (int s = 0; s < 2; ++s) {
                frag_ab a = A1[ky * 3 + kx][s];
                int off = (ky * 20 + kx) * 72 + s * 32;
                #pragma unroll
                for (int nt = 0; nt < 4; ++nt)
                    acc1[nt] = __builtin_amdgcn_mfma_f32_16x16x32_bf16(
                        a, *(const frag_ab*)&xt[pb[nt] + off], acc1[nt], 0, 0, 0);
            }

    // ---- A2 (ws) + attn A-frags (NATIVE fp32, lane-contiguous 8 floats) ----
    frag_ab A2[9][2];
    #pragma unroll
    for (int t = 0; t < 9; ++t)
        #pragma unroll
        for (int s = 0; s < 2; ++s)
            A2[t][s] = *(const frag_ab*)&wt2[(((t * 4 + wv_) * 2 + s) * 64 + lane) * 8];

    frag_ab Aq[2], Ak[2], Av[2], Ao[2];
    #pragma unroll
    for (int s = 0; s < 2; ++s) {
        int rb = (oc0 + m) * 64 + s * 32 + qd * 8;   // row-contiguous 8 ic's
        Aq[s] = pack8(*(const f32x4*)&wq[rb], *(const f32x4*)&wq[rb + 4]);
        Ak[s] = pack8(*(const f32x4*)&wk[rb], *(const f32x4*)&wk[rb + 4]);
        Av[s] = pack8(*(const f32x4*)&wv[rb], *(const f32x4*)&wv[rb + 4]);
        Ao[s] = pack8(*(const f32x4*)&wo[rb], *(const f32x4*)&wo[rb + 4]);
    }

    // ---- r1 = bf16(relu(conv1+b1)), zero at image edges ----
    {
        frag_cd b1f = *(const frag_cd*)&b1[oc0 + qd * 4];
        #pragma unroll
        for (int nt = 0; nt < 4; ++nt) {
            if (!nv[nt]) continue;
            int n = nt * 16 + m;
            int gy = y - 1 + rn_[nt];
            int gx = x0 - 1 + xs_[nt];
            bool oob = (gy < 0) | (gy > 63) | (gx < 0) | (gx > 63);
            #pragma unroll
            for (int r = 0; r < 4; ++r) {
                float v = fmaxf(acc1[nt][r] + b1f[r], 0.f);
                r1[n * 72 + oc0 + qd * 4 + r] = oob ? (unsigned short)0 : f2bf(v);
            }
        }
    }
    __syncthreads();

    // ---- conv2: 1 N-tile (16 tokens), 18 MFMA/wave ----
    frag_cd acc2 = (frag_cd){0.f, 0.f, 0.f, 0.f};
    #pragma unroll
    for (int ky = 0; ky < 3; ++ky)
        #pragma unroll
        for (int kx = 0; kx < 3; ++kx)
            #pragma unroll
            for (int s = 0; s < 2; ++s)
                acc2 = __builtin_amdgcn_mfma_f32_16x16x32_bf16(
                    A2[ky * 3 + kx][s],
                    *(const frag_ab*)&r1[(ky * 18 + m + kx) * 72 + s * 32 + qd * 8],
                    acc2, 0, 0, 0);

    // ---- h -> t_lds (fp32 residual) + tp (bf16 pairs, stride 36) ----
    {
        frag_cd b2f = *(const frag_cd*)&b2[oc0 + qd * 4];
        f32x4 hv;
        #pragma unroll
        for (int r = 0; r < 4; ++r) hv[r] = acc2[r] + b2f[r];
        *(f32x4*)&t_lds[m * 68 + oc0 + qd * 4] = hv;
        int dpb = m * 36 + (oc0 >> 1) + qd * 2;
        tp[dpb + 0] = packbf(hv[0], hv[1]);
        tp[dpb + 1] = packbf(hv[2], hv[3]);
    }
    __syncthreads();

    // ---- qkv via MFMA: wave w -> channels [16w,16w+16) x 16 tokens ----
    frag_cd qA = (frag_cd){0,0,0,0}, kA = (frag_cd){0,0,0,0}, vA = (frag_cd){0,0,0,0};
    #pragma unroll
    for (int s = 0; s < 2; ++s) {
        frag_ab hfrag = *(const frag_ab*)&tp[m * 36 + s * 16 + qd * 4];
        qA = __builtin_amdgcn_mfma_f32_16x16x32_bf16(Aq[s], hfrag, qA, 0, 0, 0);
        kA = __builtin_amdgcn_mfma_f32_16x16x32_bf16(Ak[s], hfrag, kA, 0, 0, 0);
        vA = __builtin_amdgcn_mfma_f32_16x16x32_bf16(Av[s], hfrag, vA, 0, 0, 0);
    }
    // D layout: lane(qd,m) reg r = {q,k,v}[ch=16w+4qd+r][tok=m]

    // ---- raw k,v + norm partials; ONE barrier; fold norms into exp2 scale ----
    float nq = qA[0]*qA[0] + qA[1]*qA[1] + qA[2]*qA[2] + qA[3]*qA[3];
    float nk = kA[0]*kA[0] + kA[1]*kA[1] + kA[2]*kA[2] + kA[3]*kA[3];
    nq += __shfl_xor(nq, 16); nq += __shfl_xor(nq, 32);
    nk += __shfl_xor(nk, 16); nk += __shfl_xor(nk, 32);
    if (qd == 0) nrm[wv_ * 17 + m] = (f32x2){nq, nk};
    #pragma unroll
    for (int r = 0; r < 4; ++r)
        kv[m * 66 + oc0 + qd * 4 + r] = (f32x2){kA[r], vA[r]};   // raw
    __syncthreads();

    f32x2 p0 = nrm[m],      p1 = nrm[17 + m];
    f32x2 p2 = nrm[34 + m], p3 = nrm[51 + m];
    float snq = p0.x + p1.x + p2.x + p3.x;
    float snk = p0.y + p1.y + p2.y + p3.y;
    float qs = 1.4426950408889634f /
               (fmaxf(sqrtf(snq), 1e-12f) * fmaxf(sqrtf(snk), 1e-12f));
    float qn[4];
    #pragma unroll
    for (int r = 0; r < 4; ++r) qn[r] = qA[r] * qs;

    // ---- softmax over raw k (norm scale folded into qn): scores bounded ----
    float den[4] = {0, 0, 0, 0}, num[4] = {0, 0, 0, 0};
    #pragma unroll 8
    for (int d2 = 0; d2 < 32; ++d2) {
        f32x4 K = *(const f32x4*)&kv[m * 66 + d2 * 2];   // k0,v0,k1,v1
        #pragma unroll
        for (int r = 0; r < 4; ++r) {
            float e0 = EXP2F(qn[r] * K[0]); den[r] += e0; num[r] = fmaf(e0, K[1], num[r]);
            float e1 = EXP2F(qn[r] * K[2]); den[r] += e1; num[r] = fmaf(e1, K[3], num[r]);
        }
    }
    {
        int ob = m * 36 + wv_ * 8 + qd * 2;
        o_l32[ob + 0] = packbf(num[0] / den[0], num[1] / den[1]);
        o_l32[ob + 1] = packbf(num[2] / den[2], num[3] / den[3]);
    }
    __syncthreads();

    // ---- out-proj via MFMA + bias + residual -> global ----
    frag_cd oA = (frag_cd){0, 0, 0, 0};
    #pragma unroll
    for (int s = 0; s < 2; ++s)
        oA = __builtin_amdgcn_mfma_f32_16x16x32_bf16(
            Ao[s], *(const frag_ab*)&o_l32[m * 36 + s * 16 + qd * 4], oA, 0, 0, 0);

    f32x4 bo4 = *(const f32x4*)&bo[oc0 + qd * 4];
    f32x4 res = *(const f32x4*)&t_lds[m * 68 + oc0 + qd * 4];
    #pragma unroll
    for (int r = 0; r < 4; ++r) {
        float v = oA[r] + bo4[r] + res[r];
        out[((b * 64 + oc0 + qd * 4 + r) * 64 + y) * 64 + x0 + m] = v;
    }
}

extern "C" void kernel_launch(void* const* d_in, const int* in_sizes, int n_in,
                              void* d_out, int out_size, void* d_ws, size_t ws_size,
                              hipStream_t stream) {
    const float* x  = (const float*)d_in[0];
    const float* w1 = (const float*)d_in[1];
    const float* b1 = (const float*)d_in[2];
    const float* w2 = (const float*)d_in[3];
    const float* b2 = (const float*)d_in[4];
    const float* wq = (const float*)d_in[5];
    const float* wk = (const float*)d_in[6];
    const float* wv = (const float*)d_in[7];
    const float* wo = (const float*)d_in[8];
    const float* bo = (const float*)d_in[9];
    float* out = (float*)d_out;

    // ws: wt1 bf16[36864] | wt2 bf16[36864]
    unsigned short* wt1 = (unsigned short*)d_ws;
    unsigned short* wt2 = wt1 + 36864;

    prep_w<<<288, 256, 0, stream>>>(w1, w2, wt1, wt2);
    fused_k<<<512, 256, 0, stream>>>(x, wt1, wt2, b1, b2,
                                     wq, wk, wv, wo, bo, out);
}

// Round 9
// 87.460 us; speedup vs baseline: 1.3366x; 1.0429x over previous
//
#include <hip/hip_runtime.h>
#include <hip/hip_bf16.h>

// ---------------------------------------------------------------------------
// B=2, L=64, H=W=64. Two dispatches.
//   prep_w: conv + attn weights -> bf16 MFMA A-fragment layouts in ws
//           (fused-side loads become one lane-coalesced b128 per fragment).
//   fused_k: block (b,y,16-strip): conv1 (flat-N MFMA) -> r1(LDS bf16) ->
//            conv2 (MFMA) -> h(LDS) -> qkv via MFMA -> single-barrier l2norm
//            (1/(|q||k|) folded into exp2 scale) -> softmax -> out-proj via
//            MFMA -> +bias+residual -> global store from MFMA-D layout.
// Known-bad alternatives (measured): single-dispatch device barrier (R7,
// cross-XCD acquire spin thrashes L2, kernel 59us); native fp32 attn-weight
// loads in-kernel (R8, 256B lane stride = 64 lines/instr, +3us).
// ---------------------------------------------------------------------------

#define IMG 262144

using frag_ab = __attribute__((ext_vector_type(8))) short;  // 8 bf16
using frag_cd = __attribute__((ext_vector_type(4))) float;  // 4 fp32
typedef unsigned u32x4 __attribute__((ext_vector_type(4)));
typedef float    f32x2 __attribute__((ext_vector_type(2)));
typedef float    f32x4 __attribute__((ext_vector_type(4)));

static __device__ inline unsigned short f2bf(float f) {
    unsigned u = __float_as_uint(f);
    return (unsigned short)((u + 0x7FFFu + ((u >> 16) & 1u)) >> 16);
}
static __device__ inline unsigned packbf(float a, float b) {
    return (unsigned)f2bf(a) | ((unsigned)f2bf(b) << 16);
}

#if __has_builtin(__builtin_amdgcn_exp2f)
#define EXP2F(x) __builtin_amdgcn_exp2f(x)
#else
#define EXP2F(x) __expf(0.6931471805599453f * (x))
#endif

// ---------------- prep -----------------------------------------------------
// Conv: wt[((t*4+g)*2+s)*64 + lane]*8 holds w[oc=16g+mm][ic=32s+8qq+e],
//   lane = qq*16+mm -> A-frag load is one lane-coalesced b128.
// Attn: wa[mat*4096 + ((g*2+s)*64 + lane)*8 + e], same layout, mat={q,k,v,o}.
__global__ __launch_bounds__(256) void prep_w(
    const float* __restrict__ w1, const float* __restrict__ w2,
    const float* __restrict__ wq, const float* __restrict__ wk,
    const float* __restrict__ wv, const float* __restrict__ wo,
    unsigned short* __restrict__ wt1, unsigned short* __restrict__ wt2,
    unsigned short* __restrict__ wa)
{
    int i = blockIdx.x * 256 + threadIdx.x;      // 0..90111
    if (i < 73728) {
        int mat = i >= 36864;
        int j = i - mat * 36864;
        int tap = j >> 12;
        int oc  = (j >> 6) & 63;
        int ic  = j & 63;
        const float* w = mat ? w2 : w1;
        int g = oc >> 4, mm = oc & 15;
        int s = ic >> 5, qq = (ic >> 3) & 3, e = ic & 7;
        int dst = ((((tap * 4 + g) * 2 + s) * 4 + qq) * 16 + mm) * 8 + e;
        (mat ? wt2 : wt1)[dst] = f2bf(w[(oc * 64 + ic) * 9 + tap]);
    } else {
        int a = i - 73728;                        // 0..16383
        int mat = a >> 12;
        int j = a & 4095;
        int e     = j & 7;
        int lane2 = (j >> 3) & 63;
        int gs    = j >> 9;                       // 0..7
        int g = gs >> 1, s = gs & 1;
        int qq = lane2 >> 4, mm = lane2 & 15;
        int oc = 16 * g + mm;
        int ic = 32 * s + 8 * qq + e;
        const float* w = (mat == 0) ? wq : (mat == 1) ? wk : (mat == 2) ? wv : wo;
        wa[mat * 4096 + j] = f2bf(w[oc * 64 + ic]);
    }
}

// ---------------- fully fused kernel ---------------------------------------
// Grid 512 = 2 b x 64 y x 4 xstrips(16); 2 blocks/CU. 4 waves; wave w owns
// channel slice [16w,16w+16) in all matmul phases.
__global__ __launch_bounds__(256, 2) void fused_k(
    const float* __restrict__ x,
    const unsigned short* __restrict__ wt1, const unsigned short* __restrict__ wt2,
    const float* __restrict__ b1, const float* __restrict__ b2,
    const unsigned short* __restrict__ wa, const float* __restrict__ bo,
    float* __restrict__ out)
{
    __shared__ __align__(16) unsigned short xt[5 * 20 * 72];  // 14400 B
    __shared__ __align__(16) unsigned short r1[54 * 72];      //  7776 B
    __shared__ __align__(16) float          t_lds[16 * 68];   //  4352 B
    __shared__ __align__(16) unsigned       tp[16 * 36];      //  2304 B
    __shared__ __align__(16) f32x2          kv[16 * 66];      //  8448 B (raw k,v)
    __shared__ __align__(16) unsigned       o_l32[16 * 36];   //  2304 B
    __shared__ __align__(16) f32x2          nrm[4 * 17];      //   544 B

    const int tid  = threadIdx.x;
    const int b    = blockIdx.x >> 8;
    const int y    = (blockIdx.x >> 2) & 63;
    const int x0   = (blockIdx.x & 3) * 16;
    const int wv_  = tid >> 6;
    const int lane = tid & 63;
    const int m    = lane & 15;
    const int qd   = lane >> 4;
    const int oc0  = wv_ * 16;

    // ---- A1 fragments: lane-coalesced 1KB b128 loads ----
    frag_ab A1[9][2];
    #pragma unroll
    for (int t = 0; t < 9; ++t)
        #pragma unroll
        for (int s = 0; s < 2; ++s)
            A1[t][s] = *(const frag_ab*)&wt1[(((t * 4 + wv_) * 2 + s) * 64 + lane) * 8];

    // ---- stage x tile rows y-2..y+2, xslots 0..19 (gx = x0-2+xsl) ----
    #pragma unroll
    for (int it = 0; it < 10; ++it) {
        int e    = it * 256 + tid;        // 0..2559
        int grp  = e & 7;
        int pair = e >> 3;                // 0..319
        int row = pair >> 6, ic = pair & 63;
        int yy = y - 2 + row;
        int yc = min(max(yy, 0), 63);
        int gx0 = x0 - 8 + grp * 4;
        int gxl = min(max(gx0, 0), 60);
        f32x4 v = *(const f32x4*)&x[((b * 64 + ic) * 64 + yc) * 64 + gxl];
        #pragma unroll
        for (int j = 0; j < 4; ++j) {
            int gx  = gx0 + j;
            int xsl = gx - x0 + 2;
            if (xsl < 0 || xsl >= 20) continue;
            unsigned short val =
                (yy == yc && gx >= 0 && gx <= 63) ? f2bf(v[j]) : (unsigned short)0;
            xt[(row * 20 + xsl) * 72 + ic] = val;
        }
    }
    __syncthreads();

    // ---- conv1: flat N = (row 0..2) x (xs 0..17) = 54, 4 tiles of 16 ----
    int pb[4], rn_[4], xs_[4];
    bool nv[4];
    #pragma unroll
    for (int nt = 0; nt < 4; ++nt) {
        int n  = nt * 16 + m;
        int nc = min(n, 53);
        int rr = nc / 18, xx = nc - rr * 18;
        rn_[nt] = rr; xs_[nt] = xx; nv[nt] = (n < 54);
        pb[nt] = (rr * 20 + xx) * 72 + qd * 8;
    }
    frag_cd acc1[4];
    #pragma unroll
    for (int i = 0; i < 4; ++i) acc1[i] = (frag_cd){0.f, 0.f, 0.f, 0.f};

    #pragma unroll
    for (int ky = 0; ky < 3; ++ky)
        #pragma unroll
        for (int kx = 0; kx < 3; ++kx)
            #pragma unroll
            for (int s = 0; s < 2; ++s) {
                frag_ab a = A1[ky * 3 + kx][s];
                int off = (ky * 20 + kx) * 72 + s * 32;
                #pragma unroll
                for (int nt = 0; nt < 4; ++nt)
                    acc1[nt] = __builtin_amdgcn_mfma_f32_16x16x32_bf16(
                        a, *(const frag_ab*)&xt[pb[nt] + off], acc1[nt], 0, 0, 0);
            }

    // ---- A2 + attn A-fragments from ws (lane-coalesced b128) ----
    frag_ab A2[9][2];
    #pragma unroll
    for (int t = 0; t < 9; ++t)
        #pragma unroll
        for (int s = 0; s < 2; ++s)
            A2[t][s] = *(const frag_ab*)&wt2[(((t * 4 + wv_) * 2 + s) * 64 + lane) * 8];
    frag_ab Aq[2], Ak[2], Av[2], Ao[2];
    #pragma unroll
    for (int s = 0; s < 2; ++s) {
        int off = ((wv_ * 2 + s) * 64 + lane) * 8;
        Aq[s] = *(const frag_ab*)&wa[off];
        Ak[s] = *(const frag_ab*)&wa[4096 + off];
        Av[s] = *(const frag_ab*)&wa[8192 + off];
        Ao[s] = *(const frag_ab*)&wa[12288 + off];
    }

    // ---- r1 = bf16(relu(conv1+b1)), zero at image edges ----
    {
        frag_cd b1f = *(const frag_cd*)&b1[oc0 + qd * 4];
        #pragma unroll
        for (int nt = 0; nt < 4; ++nt) {
            if (!nv[nt]) continue;
            int n = nt * 16 + m;
            int gy = y - 1 + rn_[nt];
            int gx = x0 - 1 + xs_[nt];
            bool oob = (gy < 0) | (gy > 63) | (gx < 0) | (gx > 63);
            #pragma unroll
            for (int r = 0; r < 4; ++r) {
                float v = fmaxf(acc1[nt][r] + b1f[r], 0.f);
                r1[n * 72 + oc0 + qd * 4 + r] = oob ? (unsigned short)0 : f2bf(v);
            }
        }
    }
    __syncthreads();

    // ---- conv2: 1 N-tile (16 tokens), 18 MFMA/wave ----
    frag_cd acc2 = (frag_cd){0.f, 0.f, 0.f, 0.f};
    #pragma unroll
    for (int ky = 0; ky < 3; ++ky)
        #pragma unroll
        for (int kx = 0; kx < 3; ++kx)
            #pragma unroll
            for (int s = 0; s < 2; ++s)
                acc2 = __builtin_amdgcn_mfma_f32_16x16x32_bf16(
                    A2[ky * 3 + kx][s],
                    *(const frag_ab*)&r1[(ky * 18 + m + kx) * 72 + s * 32 + qd * 8],
                    acc2, 0, 0, 0);

    // ---- h -> t_lds (fp32 residual) + tp (bf16 pairs, stride 36) ----
    {
        frag_cd b2f = *(const frag_cd*)&b2[oc0 + qd * 4];
        f32x4 hv;
        #pragma unroll
        for (int r = 0; r < 4; ++r) hv[r] = acc2[r] + b2f[r];
        *(f32x4*)&t_lds[m * 68 + oc0 + qd * 4] = hv;
        int dpb = m * 36 + (oc0 >> 1) + qd * 2;
        tp[dpb + 0] = packbf(hv[0], hv[1]);
        tp[dpb + 1] = packbf(hv[2], hv[3]);
    }
    __syncthreads();

    // ---- qkv via MFMA: wave w -> channels [16w,16w+16) x 16 tokens ----
    frag_cd qA = (frag_cd){0,0,0,0}, kA = (frag_cd){0,0,0,0}, vA = (frag_cd){0,0,0,0};
    #pragma unroll
    for (int s = 0; s < 2; ++s) {
        frag_ab hfrag = *(const frag_ab*)&tp[m * 36 + s * 16 + qd * 4];
        qA = __builtin_amdgcn_mfma_f32_16x16x32_bf16(Aq[s], hfrag, qA, 0, 0, 0);
        kA = __builtin_amdgcn_mfma_f32_16x16x32_bf16(Ak[s], hfrag, kA, 0, 0, 0);
        vA = __builtin_amdgcn_mfma_f32_16x16x32_bf16(Av[s], hfrag, vA, 0, 0, 0);
    }
    // D layout: lane(qd,m) reg r = {q,k,v}[ch=16w+4qd+r][tok=m]

    // ---- raw k,v + norm partials; ONE barrier; fold norms into exp2 scale ----
    float nq = qA[0]*qA[0] + qA[1]*qA[1] + qA[2]*qA[2] + qA[3]*qA[3];
    float nk = kA[0]*kA[0] + kA[1]*kA[1] + kA[2]*kA[2] + kA[3]*kA[3];
    nq += __shfl_xor(nq, 16); nq += __shfl_xor(nq, 32);
    nk += __shfl_xor(nk, 16); nk += __shfl_xor(nk, 32);
    if (qd == 0) nrm[wv_ * 17 + m] = (f32x2){nq, nk};
    #pragma unroll
    for (int r = 0; r < 4; ++r)
        kv[m * 66 + oc0 + qd * 4 + r] = (f32x2){kA[r], vA[r]};   // raw
    __syncthreads();

    f32x2 p0 = nrm[m],      p1 = nrm[17 + m];
    f32x2 p2 = nrm[34 + m], p3 = nrm[51 + m];
    float snq = p0.x + p1.x + p2.x + p3.x;
    float snk = p0.y + p1.y + p2.y + p3.y;
    float qs = 1.4426950408889634f /
               (fmaxf(sqrtf(snq), 1e-12f) * fmaxf(sqrtf(snk), 1e-12f));
    float qn[4];
    #pragma unroll
    for (int r = 0; r < 4; ++r) qn[r] = qA[r] * qs;

    // ---- softmax over raw k (norm scale folded into qn): scores bounded ----
    float den[4] = {0, 0, 0, 0}, num[4] = {0, 0, 0, 0};
    #pragma unroll 8
    for (int d2 = 0; d2 < 32; ++d2) {
        f32x4 K = *(const f32x4*)&kv[m * 66 + d2 * 2];   // k0,v0,k1,v1
        #pragma unroll
        for (int r = 0; r < 4; ++r) {
            float e0 = EXP2F(qn[r] * K[0]); den[r] += e0; num[r] = fmaf(e0, K[1], num[r]);
            float e1 = EXP2F(qn[r] * K[2]); den[r] += e1; num[r] = fmaf(e1, K[3], num[r]);
        }
    }
    {
        int ob = m * 36 + wv_ * 8 + qd * 2;
        o_l32[ob + 0] = packbf(num[0] / den[0], num[1] / den[1]);
        o_l32[ob + 1] = packbf(num[2] / den[2], num[3] / den[3]);
    }
    __syncthreads();

    // ---- out-proj via MFMA + bias + residual -> global ----
    frag_cd oA = (frag_cd){0, 0, 0, 0};
    #pragma unroll
    for (int s = 0; s < 2; ++s)
        oA = __builtin_amdgcn_mfma_f32_16x16x32_bf16(
            Ao[s], *(const frag_ab*)&o_l32[m * 36 + s * 16 + qd * 4], oA, 0, 0, 0);

    f32x4 bo4 = *(const f32x4*)&bo[oc0 + qd * 4];
    f32x4 res = *(const f32x4*)&t_lds[m * 68 + oc0 + qd * 4];
    #pragma unroll
    for (int r = 0; r < 4; ++r) {
        float v = oA[r] + bo4[r] + res[r];
        out[((b * 64 + oc0 + qd * 4 + r) * 64 + y) * 64 + x0 + m] = v;
    }
}

extern "C" void kernel_launch(void* const* d_in, const int* in_sizes, int n_in,
                              void* d_out, int out_size, void* d_ws, size_t ws_size,
                              hipStream_t stream) {
    const float* x  = (const float*)d_in[0];
    const float* w1 = (const float*)d_in[1];
    const float* b1 = (const float*)d_in[2];
    const float* w2 = (const float*)d_in[3];
    const float* b2 = (const float*)d_in[4];
    const float* wq = (const float*)d_in[5];
    const float* wk = (const float*)d_in[6];
    const float* wv = (const float*)d_in[7];
    const float* wo = (const float*)d_in[8];
    const float* bo = (const float*)d_in[9];
    float* out = (float*)d_out;

    // ws: wa bf16[16384] (32 KB) | wt1 bf16[36864] | wt2 bf16[36864]
    unsigned short* wa  = (unsigned short*)d_ws;
    unsigned short* wt1 = (unsigned short*)((char*)d_ws + 32768);
    unsigned short* wt2 = wt1 + 36864;

    prep_w<<<352, 256, 0, stream>>>(w1, w2, wq, wk, wv, wo, wt1, wt2, wa);
    fused_k<<<512, 256, 0, stream>>>(x, wt1, wt2, b1, b2, wa, bo, out);
}